// Round 3
// baseline (105.961 us; speedup 1.0000x reference)
//
#include <hip/hip_runtime.h>
#include <math.h>

#define NN 1000000
#define F 128
#define N0 16384
#define N1 4096

typedef __attribute__((ext_vector_type(8))) short bf16x8;
typedef __attribute__((ext_vector_type(4))) float f32x4;

__device__ inline unsigned short f2b(float f) {
    union { float f; unsigned u; } v; v.f = f;
    unsigned r = v.u + 0x7FFFu + ((v.u >> 16) & 1u);
    return (unsigned short)(r >> 16);
}

__device__ inline bf16x8 pack8(float4 a, float4 b) {
    bf16x8 r;
    r[0] = (short)f2b(a.x); r[1] = (short)f2b(a.y);
    r[2] = (short)f2b(a.z); r[3] = (short)f2b(a.w);
    r[4] = (short)f2b(b.x); r[5] = (short)f2b(b.y);
    r[6] = (short)f2b(b.z); r[7] = (short)f2b(b.w);
    return r;
}

// ---------------- map build (last-occurrence-wins scatter emulation) ---------
// maps pre-initialized to -1 via hipMemsetAsync(0xFF)

__global__ void k_prep(const int* __restrict__ ns0, const int* __restrict__ ns1,
                       int* __restrict__ map0, int* __restrict__ map1) {
    int i = blockIdx.x * blockDim.x + threadIdx.x;
    if (i < N0) atomicMax(&map0[ns0[i]], i);
    if (i < N1) atomicMax(&map1[ns1[i]], i);
}

// ---------------- q-GEMM + weighted aggregation (MFMA) -----------------------
// wave handles 2 nodes; node's 16 neighbors = 16-row M-tile; K=128, Ncols=128.

__global__ __launch_bounds__(256) void k_qagg(
    const float* __restrict__ h, const float* __restrict__ newprev,
    const int* __restrict__ mapprev,
    const int* __restrict__ nb, const float* __restrict__ nbw,
    const float* __restrict__ Qw, const float* __restrict__ Qb,
    unsigned short* __restrict__ aggb)
{
    __shared__ unsigned short lQ[128 * 128];   // 32 KB, XOR-swizzled rows
    const int tid = threadIdx.x;

    // stage Qw fp32 -> bf16 into LDS, swizzle byte ^= (j&7)<<4
    for (int c = tid; c < 2048; c += 256) {           // 16B bf16 chunks
        int j = c >> 4;
        const float4* s = (const float4*)(Qw + (size_t)j * 128 + (c & 15) * 8);
        float4 v0 = s[0], v1 = s[1];
        int byte = (c << 4) ^ ((j & 7) << 4);
        *(bf16x8*)((char*)lQ + byte) = pack8(v0, v1);
    }
    __syncthreads();

    const int wid = tid >> 6, lane = tid & 63;
    const int row = lane & 15, kg = lane >> 4;
    const long nodebase = (long)blockIdx.x * 8 + wid * 2;

    // gather + convert A fragments for both nodes (whole row held in regs)
    bf16x8 A[2][4];
#pragma unroll
    for (int nn = 0; nn < 2; ++nn) {
        long node = nodebase + nn;
        int g = nb[node * 16 + row];
        const float* src = h + (size_t)g * F;
        if (mapprev) {
            int p = mapprev[g];
            if (p >= 0) src = newprev + (size_t)p * F;
        }
        const float4* s4 = (const float4*)src;
#pragma unroll
        for (int kk = 0; kk < 4; ++kk) {
            float4 v0 = s4[kk * 8 + kg * 2];
            float4 v1 = s4[kk * 8 + kg * 2 + 1];
            A[nn][kk] = pack8(v0, v1);
        }
    }

    f32x4 acc[2][8];
#pragma unroll
    for (int nn = 0; nn < 2; ++nn)
#pragma unroll
        for (int jt = 0; jt < 8; ++jt)
            acc[nn][jt] = (f32x4){0.f, 0.f, 0.f, 0.f};

#pragma unroll
    for (int kk = 0; kk < 4; ++kk) {
        bf16x8 Bf[8];
#pragma unroll
        for (int jt = 0; jt < 8; ++jt) {
            int j = jt * 16 + row;
            int byte = ((j << 8) + (kk << 6) + (kg << 4)) ^ ((j & 7) << 4);
            Bf[jt] = *(bf16x8*)((char*)lQ + byte);
        }
#pragma unroll
        for (int jt = 0; jt < 8; ++jt) {
            acc[0][jt] = __builtin_amdgcn_mfma_f32_16x16x32_bf16(A[0][kk], Bf[jt], acc[0][jt], 0, 0, 0);
            acc[1][jt] = __builtin_amdgcn_mfma_f32_16x16x32_bf16(A[1][kk], Bf[jt], acc[1][jt], 0, 0, 0);
        }
    }

    // epilogue: bias + leaky + weighted row-reduction, safediv, bf16 store
#pragma unroll
    for (int nn = 0; nn < 2; ++nn) {
        long node = nodebase + nn;
        float w[4];
#pragma unroll
        for (int r = 0; r < 4; ++r) w[r] = nbw[node * 16 + kg * 4 + r];
        float ws = w[0] + w[1] + w[2] + w[3];
        ws += __shfl_xor(ws, 16);
        ws += __shfl_xor(ws, 32);
        float inv = (ws == 0.f) ? 1.f : 1.f / ws;
#pragma unroll
        for (int jt = 0; jt < 8; ++jt) {
            float qb = Qb[jt * 16 + row];
            float t = 0.f;
#pragma unroll
            for (int r = 0; r < 4; ++r) {
                float v = acc[nn][jt][r] + qb;
                v = v > 0.f ? v : 0.01f * v;
                t = fmaf(w[r], v, t);
            }
            t += __shfl_xor(t, 16);
            t += __shfl_xor(t, 32);
            if (lane < 16) aggb[node * 128 + jt * 16 + lane] = f2b(t * inv);
        }
    }
}

// ---------------- dense GEMM: leaky(cat(self, agg) @ Ww^T + Wb), normalize ---
// block = 16 nodes (one M-tile); 4 waves split the 128 output columns (2 jt each).

__global__ __launch_bounds__(256) void k_dense(
    const float* __restrict__ h, const float* __restrict__ newprev,
    const int* __restrict__ mapprev,
    const int* __restrict__ nodeset, const unsigned short* __restrict__ aggb,
    const float* __restrict__ Ww, const float* __restrict__ Wb,
    float* __restrict__ outnew)
{
    __shared__ unsigned short lW[128 * 256];   // 64 KB, XOR-swizzled rows
    __shared__ float sred[4][16];
    const int tid = threadIdx.x;

    for (int c = tid; c < 4096; c += 256) {
        int j = c >> 5;
        const float4* s = (const float4*)(Ww + (size_t)j * 256 + (c & 31) * 8);
        float4 v0 = s[0], v1 = s[1];
        int byte = (c << 4) ^ ((j & 7) << 4);
        *(bf16x8*)((char*)lW + byte) = pack8(v0, v1);
    }
    __syncthreads();

    const int wid = tid >> 6, lane = tid & 63;
    const int col = lane & 15, kg = lane >> 4;
    const long mbase = (long)blockIdx.x * 16;
    const long m = mbase + col;                 // A-fragment row = lane&15

    int gs = nodeset[m];
    const float* src = h + (size_t)gs * F;
    if (mapprev) {
        int p = mapprev[gs];
        if (p >= 0) src = newprev + (size_t)p * F;
    }

    bf16x8 A[8];
    const float4* s4 = (const float4*)src;
#pragma unroll
    for (int kk = 0; kk < 4; ++kk) {
        float4 v0 = s4[kk * 8 + kg * 2];
        float4 v1 = s4[kk * 8 + kg * 2 + 1];
        A[kk] = pack8(v0, v1);
    }
    const bf16x8* a4 = (const bf16x8*)(aggb + m * 128);
#pragma unroll
    for (int kk = 0; kk < 4; ++kk) A[4 + kk] = a4[kk * 4 + kg];

    f32x4 acc[2];
    acc[0] = (f32x4){0.f, 0.f, 0.f, 0.f};
    acc[1] = (f32x4){0.f, 0.f, 0.f, 0.f};

#pragma unroll
    for (int kk = 0; kk < 8; ++kk) {
#pragma unroll
        for (int jl = 0; jl < 2; ++jl) {
            int j = (wid * 2 + jl) * 16 + col;
            int byte = ((j << 9) + (kk << 6) + (kg << 4)) ^ ((j & 7) << 4);
            bf16x8 Bf = *(bf16x8*)((char*)lW + byte);
            acc[jl] = __builtin_amdgcn_mfma_f32_16x16x32_bf16(A[kk], Bf, acc[jl], 0, 0, 0);
        }
    }

    // epilogue: bias + leaky, partial row sum-of-squares over this wave's 32 cols
    float ss[4] = {0.f, 0.f, 0.f, 0.f};
#pragma unroll
    for (int jl = 0; jl < 2; ++jl) {
        float wb = Wb[(wid * 2 + jl) * 16 + col];
#pragma unroll
        for (int r = 0; r < 4; ++r) {
            float v = acc[jl][r] + wb;
            v = v > 0.f ? v : 0.01f * v;
            acc[jl][r] = v;
            ss[r] = fmaf(v, v, ss[r]);
        }
    }
#pragma unroll
    for (int r = 0; r < 4; ++r) {
        ss[r] += __shfl_xor(ss[r], 1);
        ss[r] += __shfl_xor(ss[r], 2);
        ss[r] += __shfl_xor(ss[r], 4);
        ss[r] += __shfl_xor(ss[r], 8);
    }
    if (col == 0) {
#pragma unroll
        for (int r = 0; r < 4; ++r) sred[wid][kg * 4 + r] = ss[r];
    }
    __syncthreads();
    float invn[4];
#pragma unroll
    for (int r = 0; r < 4; ++r) {
        float s = sred[0][kg * 4 + r] + sred[1][kg * 4 + r] +
                  sred[2][kg * 4 + r] + sred[3][kg * 4 + r];
        float n = sqrtf(s);
        invn[r] = (n == 0.f) ? 1.f : 1.f / n;
    }
#pragma unroll
    for (int jl = 0; jl < 2; ++jl)
#pragma unroll
        for (int r = 0; r < 4; ++r)
            outnew[(size_t)(mbase + kg * 4 + r) * F + (wid * 2 + jl) * 16 + col] = acc[jl][r] * invn[r];
}

// ---------------- duplicate-row fixup on d_out -------------------------------
// out[i] must be new1[map1[ns1[i]]]; dense1 wrote new1[i] at out[i]. Rows that
// are last-occurrences are never rewritten, so reading out[p] is race-free.

__global__ void k_fix(const int* __restrict__ map1, const int* __restrict__ ns1,
                      float* __restrict__ out, int n) {
    int i = blockIdx.x * blockDim.x + threadIdx.x;
    if (i < n) {
        int p = map1[ns1[i]];
        if (p != i) {
            float4* o = (float4*)out;
#pragma unroll
            for (int c = 0; c < 32; ++c) o[(size_t)i * 32 + c] = o[(size_t)p * 32 + c];
        }
    }
}

// ---------------- launcher ---------------------------------------------------

extern "C" void kernel_launch(void* const* d_in, const int* in_sizes, int n_in,
                              void* d_out, int out_size, void* d_ws, size_t ws_size,
                              hipStream_t stream) {
    const float* h    = (const float*)d_in[0];
    const float* Qw0  = (const float*)d_in[1];
    const float* Qb0  = (const float*)d_in[2];
    const float* Ww0  = (const float*)d_in[3];
    const float* Wb0  = (const float*)d_in[4];
    const float* Qw1  = (const float*)d_in[5];
    const float* Qb1  = (const float*)d_in[6];
    const float* Ww1  = (const float*)d_in[7];
    const float* Wb1  = (const float*)d_in[8];
    const int*   ns0  = (const int*)d_in[9];
    const int*   nb0  = (const int*)d_in[10];
    const float* nbw0 = (const float*)d_in[11];
    const int*   ns1  = (const int*)d_in[12];
    const int*   nb1  = (const int*)d_in[13];
    const float* nbw1 = (const float*)d_in[14];

    // ws: map0 | map1 | new0 f32 | aggb bf16
    int* map0 = (int*)d_ws;
    int* map1 = map0 + NN;
    float* new0 = (float*)(map1 + NN);
    unsigned short* aggb = (unsigned short*)(new0 + (size_t)N0 * F);

    hipMemsetAsync(map0, 0xFF, (size_t)2 * NN * sizeof(int), stream);
    k_prep<<<N0 / 256, 256, 0, stream>>>(ns0, ns1, map0, map1);

    // layer 0 (reads original h only; independent of maps)
    k_qagg<<<N0 / 8, 256, 0, stream>>>(h, nullptr, nullptr, nb0, nbw0, Qw0, Qb0, aggb);
    k_dense<<<N0 / 16, 256, 0, stream>>>(h, nullptr, nullptr, ns0, aggb, Ww0, Wb0, new0);

    // layer 1 (h with nodeset0 rows redirected to new0 via map0)
    k_qagg<<<N1 / 8, 256, 0, stream>>>(h, new0, map0, nb1, nbw1, Qw1, Qb1, aggb);
    k_dense<<<N1 / 16, 256, 0, stream>>>(h, new0, map0, ns1, aggb, Ww1, Wb1, (float*)d_out);

    k_fix<<<(N1 + 255) / 256, 256, 0, stream>>>(map1, ns1, (float*)d_out, N1);
}

// Round 4
// 95.079 us; speedup vs baseline: 1.1145x; 1.1145x over previous
//
#include <hip/hip_runtime.h>
#include <hip/hip_bf16.h>
#include <math.h>

#define NN 1000000
#define F 128
#define N0 16384
#define N1 4096

typedef __attribute__((ext_vector_type(8))) short bf16x8;
typedef __attribute__((ext_vector_type(4))) float f32x4;

__device__ inline unsigned short f2b(float f) {
    union { float f; unsigned u; } v; v.f = f;
    unsigned r = v.u + 0x7FFFu + ((v.u >> 16) & 1u);
    return (unsigned short)(r >> 16);
}

__device__ inline bf16x8 pack8(float4 a, float4 b) {
    union { __hip_bfloat162 h2[4]; bf16x8 v; } u;
    u.h2[0] = __float22bfloat162_rn(make_float2(a.x, a.y));
    u.h2[1] = __float22bfloat162_rn(make_float2(a.z, a.w));
    u.h2[2] = __float22bfloat162_rn(make_float2(b.x, b.y));
    u.h2[3] = __float22bfloat162_rn(make_float2(b.z, b.w));
    return u.v;
}

// ---------------- prep: maps (last-wins) + weight bf16 conversion ------------
// maps pre-initialized to -1 via hipMemsetAsync(0xFF)

__global__ void k_prep(const int* __restrict__ ns0, const int* __restrict__ ns1,
                       int* __restrict__ map0, int* __restrict__ map1,
                       const float* __restrict__ Qw0, const float* __restrict__ Qw1,
                       const float* __restrict__ Ww0, const float* __restrict__ Ww1,
                       unsigned short* __restrict__ Qw0b, unsigned short* __restrict__ Qw1b,
                       unsigned short* __restrict__ Ww0b, unsigned short* __restrict__ Ww1b) {
    int i = blockIdx.x * blockDim.x + threadIdx.x;
    int nt = gridDim.x * blockDim.x;
    if (i < N0) atomicMax(&map0[ns0[i]], i);
    if (i < N1) atomicMax(&map1[ns1[i]], i);
    for (int j = i; j < 128 * 128; j += nt) { Qw0b[j] = f2b(Qw0[j]); Qw1b[j] = f2b(Qw1[j]); }
    for (int j = i; j < 128 * 256; j += nt) { Ww0b[j] = f2b(Ww0[j]); Ww1b[j] = f2b(Ww1[j]); }
}

// ---------------- q-GEMM + weighted aggregation (MFMA) -----------------------
// wave handles 2 nodes; node's 16 neighbors = 16-row M-tile; K=128, Ncols=128.

__global__ __launch_bounds__(256) void k_qagg(
    const float* __restrict__ h, const float* __restrict__ newprev,
    const int* __restrict__ mapprev,
    const int* __restrict__ nb, const float* __restrict__ nbw,
    const unsigned short* __restrict__ Qwb, const float* __restrict__ Qb,
    unsigned short* __restrict__ aggb)
{
    __shared__ unsigned short lQ[128 * 128];   // 32 KB, XOR-swizzled rows
    const int tid = threadIdx.x;
    const int wid = tid >> 6, lane = tid & 63;
    const int row = lane & 15, kg = lane >> 4;
    const long nodebase = (long)blockIdx.x * 8 + wid * 2;

    // issue gathers FIRST (fp32 into regs) so HBM latency hides under staging
    float4 av[2][8];
#pragma unroll
    for (int nn = 0; nn < 2; ++nn) {
        long node = nodebase + nn;
        int g = nb[node * 16 + row];
        const float* src = h + (size_t)g * F;
        if (mapprev) {
            int p = mapprev[g];
            if (p >= 0) src = newprev + (size_t)p * F;
        }
        const float4* s4 = (const float4*)src;
#pragma unroll
        for (int kk = 0; kk < 4; ++kk) {
            av[nn][kk * 2]     = s4[kk * 8 + kg * 2];
            av[nn][kk * 2 + 1] = s4[kk * 8 + kg * 2 + 1];
        }
    }

    // stage Qw (bf16 pre-converted) into LDS, swizzle byte ^= (j&7)<<4
    for (int c = tid; c < 2048; c += 256) {
        int j = c >> 4;
        uint4 v = ((const uint4*)Qwb)[c];
        *(uint4*)((char*)lQ + ((c << 4) ^ ((j & 7) << 4))) = v;
    }
    __syncthreads();

    bf16x8 A[2][4];
#pragma unroll
    for (int nn = 0; nn < 2; ++nn)
#pragma unroll
        for (int kk = 0; kk < 4; ++kk)
            A[nn][kk] = pack8(av[nn][kk * 2], av[nn][kk * 2 + 1]);

    f32x4 acc[2][8];
#pragma unroll
    for (int nn = 0; nn < 2; ++nn)
#pragma unroll
        for (int jt = 0; jt < 8; ++jt)
            acc[nn][jt] = (f32x4){0.f, 0.f, 0.f, 0.f};

#pragma unroll
    for (int kk = 0; kk < 4; ++kk) {
        bf16x8 Bf[8];
#pragma unroll
        for (int jt = 0; jt < 8; ++jt) {
            int j = jt * 16 + row;
            int byte = ((j << 8) + (kk << 6) + (kg << 4)) ^ ((j & 7) << 4);
            Bf[jt] = *(bf16x8*)((char*)lQ + byte);
        }
#pragma unroll
        for (int jt = 0; jt < 8; ++jt) {
            acc[0][jt] = __builtin_amdgcn_mfma_f32_16x16x32_bf16(A[0][kk], Bf[jt], acc[0][jt], 0, 0, 0);
            acc[1][jt] = __builtin_amdgcn_mfma_f32_16x16x32_bf16(A[1][kk], Bf[jt], acc[1][jt], 0, 0, 0);
        }
    }

    // epilogue: bias + leaky + weighted row-reduction, safediv, bf16 store
#pragma unroll
    for (int nn = 0; nn < 2; ++nn) {
        long node = nodebase + nn;
        float w[4];
#pragma unroll
        for (int r = 0; r < 4; ++r) w[r] = nbw[node * 16 + kg * 4 + r];
        float ws = w[0] + w[1] + w[2] + w[3];
        ws += __shfl_xor(ws, 16);
        ws += __shfl_xor(ws, 32);
        float inv = (ws == 0.f) ? 1.f : 1.f / ws;
#pragma unroll
        for (int jt = 0; jt < 8; ++jt) {
            float qb = Qb[jt * 16 + row];
            float t = 0.f;
#pragma unroll
            for (int r = 0; r < 4; ++r) {
                float v = acc[nn][jt][r] + qb;
                v = v > 0.f ? v : 0.01f * v;
                t = fmaf(w[r], v, t);
            }
            t += __shfl_xor(t, 16);
            t += __shfl_xor(t, 32);
            if (lane < 16) aggb[node * 128 + jt * 16 + lane] = f2b(t * inv);
        }
    }
}

// ---------------- dense GEMM: leaky(cat(self, agg) @ Ww^T + Wb), normalize ---
// wave = 16 nodes (one M-tile), K=256 (self 128 | agg 128), Ncols=128.

__global__ __launch_bounds__(256) void k_dense(
    const float* __restrict__ h, const float* __restrict__ newprev,
    const int* __restrict__ mapprev,
    const int* __restrict__ nodeset, const unsigned short* __restrict__ aggb,
    const unsigned short* __restrict__ Wwb, const float* __restrict__ Wb,
    float* __restrict__ outnew)
{
    __shared__ unsigned short lW[128 * 256];   // 64 KB, XOR-swizzled rows
    const int tid = threadIdx.x;
    const int wid = tid >> 6, lane = tid & 63;
    const int row = lane & 15, kg = lane >> 4;
    const long mbase = (long)blockIdx.x * 64 + wid * 16;
    const long m = mbase + row;

    // issue self-row gather first
    int gs = nodeset[m];
    const float* src = h + (size_t)gs * F;
    if (mapprev) {
        int p = mapprev[gs];
        if (p >= 0) src = newprev + (size_t)p * F;
    }
    float4 av[8];
    const float4* s4 = (const float4*)src;
#pragma unroll
    for (int kk = 0; kk < 4; ++kk) {
        av[kk * 2]     = s4[kk * 8 + kg * 2];
        av[kk * 2 + 1] = s4[kk * 8 + kg * 2 + 1];
    }
    bf16x8 Aagg[4];
    const bf16x8* a4 = (const bf16x8*)(aggb + m * 128);
#pragma unroll
    for (int kk = 0; kk < 4; ++kk) Aagg[kk] = a4[kk * 4 + kg];

    // stage Ww (bf16 pre-converted) into swizzled LDS
    for (int c = tid; c < 4096; c += 256) {
        int j = c >> 5;
        uint4 v = ((const uint4*)Wwb)[c];
        *(uint4*)((char*)lW + ((c << 4) ^ ((j & 7) << 4))) = v;
    }
    __syncthreads();

    bf16x8 A[8];
#pragma unroll
    for (int kk = 0; kk < 4; ++kk) {
        A[kk] = pack8(av[kk * 2], av[kk * 2 + 1]);
        A[4 + kk] = Aagg[kk];
    }

    f32x4 acc[8];
#pragma unroll
    for (int jt = 0; jt < 8; ++jt) acc[jt] = (f32x4){0.f, 0.f, 0.f, 0.f};

#pragma unroll
    for (int kk = 0; kk < 8; ++kk) {
        bf16x8 Bf[8];
#pragma unroll
        for (int jt = 0; jt < 8; ++jt) {
            int j = jt * 16 + row;
            int byte = ((j << 9) + (kk << 6) + (kg << 4)) ^ ((j & 7) << 4);
            Bf[jt] = *(bf16x8*)((char*)lW + byte);
        }
#pragma unroll
        for (int jt = 0; jt < 8; ++jt)
            acc[jt] = __builtin_amdgcn_mfma_f32_16x16x32_bf16(A[kk], Bf[jt], acc[jt], 0, 0, 0);
    }

    // epilogue: bias + leaky, row sum-of-squares, normalize, store
    float ss[4] = {0.f, 0.f, 0.f, 0.f};
#pragma unroll
    for (int jt = 0; jt < 8; ++jt) {
        float wb = Wb[jt * 16 + row];
#pragma unroll
        for (int r = 0; r < 4; ++r) {
            float v = acc[jt][r] + wb;
            v = v > 0.f ? v : 0.01f * v;
            acc[jt][r] = v;
            ss[r] = fmaf(v, v, ss[r]);
        }
    }
#pragma unroll
    for (int r = 0; r < 4; ++r) {
        ss[r] += __shfl_xor(ss[r], 1);
        ss[r] += __shfl_xor(ss[r], 2);
        ss[r] += __shfl_xor(ss[r], 4);
        ss[r] += __shfl_xor(ss[r], 8);
    }
    float invn[4];
#pragma unroll
    for (int r = 0; r < 4; ++r) {
        float n = sqrtf(ss[r]);
        invn[r] = (n == 0.f) ? 1.f : 1.f / n;
    }
#pragma unroll
    for (int jt = 0; jt < 8; ++jt)
#pragma unroll
        for (int r = 0; r < 4; ++r)
            outnew[(size_t)(mbase + kg * 4 + r) * F + jt * 16 + row] = acc[jt][r] * invn[r];
}

// ---------------- duplicate-row fixup on d_out -------------------------------
// out[i] must be new1[map1[ns1[i]]]; dense1 wrote new1[i] at out[i]. Rows that
// are last-occurrences are never rewritten, so reading out[p] is race-free.

__global__ void k_fix(const int* __restrict__ map1, const int* __restrict__ ns1,
                      float* __restrict__ out, int n) {
    int i = blockIdx.x * blockDim.x + threadIdx.x;
    if (i < n) {
        int p = map1[ns1[i]];
        if (p != i) {
            float4* o = (float4*)out;
#pragma unroll
            for (int c = 0; c < 32; ++c) o[(size_t)i * 32 + c] = o[(size_t)p * 32 + c];
        }
    }
}

// ---------------- launcher ---------------------------------------------------

extern "C" void kernel_launch(void* const* d_in, const int* in_sizes, int n_in,
                              void* d_out, int out_size, void* d_ws, size_t ws_size,
                              hipStream_t stream) {
    const float* h    = (const float*)d_in[0];
    const float* Qw0  = (const float*)d_in[1];
    const float* Qb0  = (const float*)d_in[2];
    const float* Ww0  = (const float*)d_in[3];
    const float* Wb0  = (const float*)d_in[4];
    const float* Qw1  = (const float*)d_in[5];
    const float* Qb1  = (const float*)d_in[6];
    const float* Ww1  = (const float*)d_in[7];
    const float* Wb1  = (const float*)d_in[8];
    const int*   ns0  = (const int*)d_in[9];
    const int*   nb0  = (const int*)d_in[10];
    const float* nbw0 = (const float*)d_in[11];
    const int*   ns1  = (const int*)d_in[12];
    const int*   nb1  = (const int*)d_in[13];
    const float* nbw1 = (const float*)d_in[14];

    // ws: map0 | map1 | new0 f32 | aggb bf16 | Qw0b | Qw1b | Ww0b | Ww1b
    int* map0 = (int*)d_ws;
    int* map1 = map0 + NN;
    float* new0 = (float*)(map1 + NN);
    unsigned short* aggb = (unsigned short*)(new0 + (size_t)N0 * F);
    unsigned short* Qw0b = aggb + (size_t)N0 * F;
    unsigned short* Qw1b = Qw0b + 128 * 128;
    unsigned short* Ww0b = Qw1b + 128 * 128;
    unsigned short* Ww1b = Ww0b + 128 * 256;

    hipMemsetAsync(map0, 0xFF, (size_t)2 * NN * sizeof(int), stream);
    k_prep<<<64, 256, 0, stream>>>(ns0, ns1, map0, map1,
                                   Qw0, Qw1, Ww0, Ww1, Qw0b, Qw1b, Ww0b, Ww1b);

    // layer 0
    k_qagg<<<N0 / 8, 256, 0, stream>>>(h, nullptr, nullptr, nb0, nbw0, Qw0b, Qb0, aggb);
    k_dense<<<N0 / 64, 256, 0, stream>>>(h, nullptr, nullptr, ns0, aggb, Ww0b, Wb0, new0);

    // layer 1 (h with nodeset0 rows redirected to new0 via map0)
    k_qagg<<<N1 / 8, 256, 0, stream>>>(h, new0, map0, nb1, nbw1, Qw1b, Qb1, aggb);
    k_dense<<<N1 / 64, 256, 0, stream>>>(h, new0, map0, ns1, aggb, Ww1b, Wb1, (float*)d_out);

    k_fix<<<(N1 + 255) / 256, 256, 0, stream>>>(map1, ns1, (float*)d_out, N1);
}

// Round 5
// 91.441 us; speedup vs baseline: 1.1588x; 1.0398x over previous
//
#include <hip/hip_runtime.h>
#include <hip/hip_bf16.h>
#include <math.h>

#define NN 1000000
#define F 128
#define N0 16384
#define N1 4096

typedef __attribute__((ext_vector_type(8))) short bf16x8;
typedef __attribute__((ext_vector_type(4))) float f32x4;

__device__ inline unsigned short f2b(float f) {
    union { float f; unsigned u; } v; v.f = f;
    unsigned r = v.u + 0x7FFFu + ((v.u >> 16) & 1u);
    return (unsigned short)(r >> 16);
}

__device__ inline bf16x8 pack8(float4 a, float4 b) {
    union { __hip_bfloat162 h2[4]; bf16x8 v; } u;
    u.h2[0] = __float22bfloat162_rn(make_float2(a.x, a.y));
    u.h2[1] = __float22bfloat162_rn(make_float2(a.z, a.w));
    u.h2[2] = __float22bfloat162_rn(make_float2(b.x, b.y));
    u.h2[3] = __float22bfloat162_rn(make_float2(b.z, b.w));
    return u.v;
}

// ---------------- prep: maps (last-wins) + weight bf16 conversion ------------
// maps pre-initialized to -1 via hipMemsetAsync(0xFF)

__global__ void k_prep(const int* __restrict__ ns0, const int* __restrict__ ns1,
                       int* __restrict__ map0, int* __restrict__ map1,
                       const float* __restrict__ Qw0, const float* __restrict__ Qw1,
                       const float* __restrict__ Ww0, const float* __restrict__ Ww1,
                       unsigned short* __restrict__ Qw0b, unsigned short* __restrict__ Qw1b,
                       unsigned short* __restrict__ Ww0b, unsigned short* __restrict__ Ww1b) {
    int i = blockIdx.x * blockDim.x + threadIdx.x;
    int nt = gridDim.x * blockDim.x;
    if (i < N0) atomicMax(&map0[ns0[i]], i);
    if (i < N1) atomicMax(&map1[ns1[i]], i);
    for (int j = i; j < 128 * 128; j += nt) { Qw0b[j] = f2b(Qw0[j]); Qw1b[j] = f2b(Qw1[j]); }
    for (int j = i; j < 128 * 256; j += nt) { Ww0b[j] = f2b(Ww0[j]); Ww1b[j] = f2b(Ww1[j]); }
}

// ---------------- fused layer: qagg (phase 1) + dense (phase 2) --------------
// block = 512 threads (8 waves) = 16 nodes.
// phase 1: wave handles 2 nodes; 16 neighbors = M-tile; K=128 -> agg in LDS.
// phase 2: each wave takes 16 output cols of the 16x256 dense GEMM.

__global__ __launch_bounds__(512) void k_layer(
    const float* __restrict__ h, const unsigned short* __restrict__ newprevb,
    const int* __restrict__ mapprev,
    const int* __restrict__ nodeset, const int* __restrict__ nb,
    const float* __restrict__ nbw,
    const unsigned short* __restrict__ Qwb, const float* __restrict__ Qb,
    const unsigned short* __restrict__ Wwb, const float* __restrict__ Wb,
    float* __restrict__ outf, unsigned short* __restrict__ outb)
{
    __shared__ unsigned short lQ[128 * 128];   // 32 KB Qw bf16, XOR-swizzled
    __shared__ unsigned short lA[16 * 256];    // 8 KB: [node][self 0..127 | agg 128..255]
    __shared__ float sred[8][16];
    const int tid = threadIdx.x;
    const int wid = tid >> 6, lane = tid & 63;
    const int row = lane & 15, kg = lane >> 4;
    const long mbase = (long)blockIdx.x * 16;

    // ---- issue self-row gather (threads 0..127; 8 lanes per node row)
    float4 sv[4];
    uint4 sb[2];
    bool sredir = false;
    const int sq = tid & 7;
    if (tid < 128) {
        int sr = tid >> 3;
        int gs = nodeset[mbase + sr];
        int p = mapprev ? mapprev[gs] : -1;
        if (p >= 0) {
            sredir = true;
            const uint4* s = (const uint4*)(newprevb + (size_t)p * F + sq * 16);
            sb[0] = s[0]; sb[1] = s[1];
        } else {
            const float4* s = (const float4*)(h + (size_t)gs * F + sq * 16);
            sv[0] = s[0]; sv[1] = s[1]; sv[2] = s[2]; sv[3] = s[3];
        }
    }

    // ---- issue neighbor gathers (2 nodes per wave)
    const long nodebase = mbase + wid * 2;
    float4 av[2][8];
    bf16x8 Ab[2][4];
    bool redir[2];
#pragma unroll
    for (int nn = 0; nn < 2; ++nn) {
        long node = nodebase + nn;
        int g = nb[node * 16 + row];
        int p = mapprev ? mapprev[g] : -1;
        redir[nn] = (p >= 0);
        if (p >= 0) {
            const bf16x8* s = (const bf16x8*)(newprevb + (size_t)p * F);
#pragma unroll
            for (int kk = 0; kk < 4; ++kk) Ab[nn][kk] = s[kk * 4 + kg];
        } else {
            const float4* s4 = (const float4*)(h + (size_t)g * F);
#pragma unroll
            for (int kk = 0; kk < 4; ++kk) {
                av[nn][kk * 2]     = s4[kk * 8 + kg * 2];
                av[nn][kk * 2 + 1] = s4[kk * 8 + kg * 2 + 1];
            }
        }
    }

    // ---- stage Qw into swizzled LDS (latency of gathers hides under this)
    for (int c = tid; c < 2048; c += 512) {
        int j = c >> 4;
        uint4 v = ((const uint4*)Qwb)[c];
        *(uint4*)((char*)lQ + ((c << 4) ^ ((j & 7) << 4))) = v;
    }

    // ---- write self rows to lA (bf16, swizzled)
    if (tid < 128) {
        int sr = tid >> 3;
        int b0 = sr * 512 + sq * 32;
        int swz = (sr & 7) << 4;
        if (sredir) {
            *(uint4*)((char*)lA + (b0 ^ swz)) = sb[0];
            *(uint4*)((char*)lA + ((b0 + 16) ^ swz)) = sb[1];
        } else {
            *(bf16x8*)((char*)lA + (b0 ^ swz)) = pack8(sv[0], sv[1]);
            *(bf16x8*)((char*)lA + ((b0 + 16) ^ swz)) = pack8(sv[2], sv[3]);
        }
    }

    // ---- pack neighbor rows fp32 -> bf16
#pragma unroll
    for (int nn = 0; nn < 2; ++nn)
        if (!redir[nn]) {
#pragma unroll
            for (int kk = 0; kk < 4; ++kk)
                Ab[nn][kk] = pack8(av[nn][kk * 2], av[nn][kk * 2 + 1]);
        }
    __syncthreads();

    // ---- phase 1: qagg MFMA
    f32x4 acc[2][8];
#pragma unroll
    for (int nn = 0; nn < 2; ++nn)
#pragma unroll
        for (int jt = 0; jt < 8; ++jt)
            acc[nn][jt] = (f32x4){0.f, 0.f, 0.f, 0.f};

#pragma unroll
    for (int kk = 0; kk < 4; ++kk) {
        bf16x8 Bf[8];
#pragma unroll
        for (int jt = 0; jt < 8; ++jt) {
            int j = jt * 16 + row;
            int byte = ((j << 8) + (kk << 6) + (kg << 4)) ^ ((j & 7) << 4);
            Bf[jt] = *(bf16x8*)((char*)lQ + byte);
        }
#pragma unroll
        for (int jt = 0; jt < 8; ++jt) {
            acc[0][jt] = __builtin_amdgcn_mfma_f32_16x16x32_bf16(Ab[0][kk], Bf[jt], acc[0][jt], 0, 0, 0);
            acc[1][jt] = __builtin_amdgcn_mfma_f32_16x16x32_bf16(Ab[1][kk], Bf[jt], acc[1][jt], 0, 0, 0);
        }
    }

    // ---- phase 1 epilogue: bias+leaky+weighted reduce -> lA agg region (bf16)
#pragma unroll
    for (int nn = 0; nn < 2; ++nn) {
        long node = nodebase + nn;
        int nl = wid * 2 + nn;
        float w[4];
#pragma unroll
        for (int r = 0; r < 4; ++r) w[r] = nbw[node * 16 + kg * 4 + r];
        float ws = w[0] + w[1] + w[2] + w[3];
        ws += __shfl_xor(ws, 16);
        ws += __shfl_xor(ws, 32);
        float inv = (ws == 0.f) ? 1.f : 1.f / ws;
#pragma unroll
        for (int jt = 0; jt < 8; ++jt) {
            float qb = Qb[jt * 16 + row];
            float t = 0.f;
#pragma unroll
            for (int r = 0; r < 4; ++r) {
                float v = acc[nn][jt][r] + qb;
                v = v > 0.f ? v : 0.01f * v;
                t = fmaf(w[r], v, t);
            }
            t += __shfl_xor(t, 16);
            t += __shfl_xor(t, 32);
            if (lane < 16) {
                int byte = (nl * 512 + 256 + jt * 32 + lane * 2) ^ ((nl & 7) << 4);
                *(unsigned short*)((char*)lA + byte) = f2b(t * inv);
            }
        }
    }
    __syncthreads();

    // ---- phase 2: dense 16x256 @ Ww^T, this wave = 16 output cols
    const int j = wid * 16 + row;
    f32x4 dacc = (f32x4){0.f, 0.f, 0.f, 0.f};
#pragma unroll
    for (int kk = 0; kk < 8; ++kk) {
        bf16x8 a = *(bf16x8*)((char*)lA + ((row * 512 + kk * 64 + kg * 16) ^ ((row & 7) << 4)));
        bf16x8 b = ((const bf16x8*)(Wwb + (size_t)j * 256))[kk * 4 + kg];
        dacc = __builtin_amdgcn_mfma_f32_16x16x32_bf16(a, b, dacc, 0, 0, 0);
    }

    float wb = Wb[j];
    float ss[4];
#pragma unroll
    for (int r = 0; r < 4; ++r) {
        float v = dacc[r] + wb;
        v = v > 0.f ? v : 0.01f * v;
        dacc[r] = v;
        ss[r] = v * v;
    }
#pragma unroll
    for (int r = 0; r < 4; ++r) {
        ss[r] += __shfl_xor(ss[r], 1);
        ss[r] += __shfl_xor(ss[r], 2);
        ss[r] += __shfl_xor(ss[r], 4);
        ss[r] += __shfl_xor(ss[r], 8);
    }
    if (row == 0) {
#pragma unroll
        for (int r = 0; r < 4; ++r) sred[wid][kg * 4 + r] = ss[r];
    }
    __syncthreads();
    float invn[4];
#pragma unroll
    for (int r = 0; r < 4; ++r) {
        float s = 0.f;
#pragma unroll
        for (int w8 = 0; w8 < 8; ++w8) s += sred[w8][kg * 4 + r];
        float n = sqrtf(s);
        invn[r] = (n == 0.f) ? 1.f : 1.f / n;
    }
    if (outf) {
#pragma unroll
        for (int r = 0; r < 4; ++r)
            outf[(size_t)(mbase + kg * 4 + r) * F + j] = dacc[r] * invn[r];
    } else {
#pragma unroll
        for (int r = 0; r < 4; ++r)
            outb[(size_t)(mbase + kg * 4 + r) * F + j] = f2b(dacc[r] * invn[r]);
    }
}

// ---------------- duplicate-row fixup on d_out -------------------------------

__global__ void k_fix(const int* __restrict__ map1, const int* __restrict__ ns1,
                      float* __restrict__ out, int n) {
    int i = blockIdx.x * blockDim.x + threadIdx.x;
    if (i < n) {
        int p = map1[ns1[i]];
        if (p != i) {
            float4* o = (float4*)out;
#pragma unroll
            for (int c = 0; c < 32; ++c) o[(size_t)i * 32 + c] = o[(size_t)p * 32 + c];
        }
    }
}

// ---------------- launcher ---------------------------------------------------

extern "C" void kernel_launch(void* const* d_in, const int* in_sizes, int n_in,
                              void* d_out, int out_size, void* d_ws, size_t ws_size,
                              hipStream_t stream) {
    const float* h    = (const float*)d_in[0];
    const float* Qw0  = (const float*)d_in[1];
    const float* Qb0  = (const float*)d_in[2];
    const float* Ww0  = (const float*)d_in[3];
    const float* Wb0  = (const float*)d_in[4];
    const float* Qw1  = (const float*)d_in[5];
    const float* Qb1  = (const float*)d_in[6];
    const float* Ww1  = (const float*)d_in[7];
    const float* Wb1  = (const float*)d_in[8];
    const int*   ns0  = (const int*)d_in[9];
    const int*   nb0  = (const int*)d_in[10];
    const float* nbw0 = (const float*)d_in[11];
    const int*   ns1  = (const int*)d_in[12];
    const int*   nb1  = (const int*)d_in[13];
    const float* nbw1 = (const float*)d_in[14];

    // ws: map0 | map1 | new0b bf16 | Qw0b | Qw1b | Ww0b | Ww1b
    int* map0 = (int*)d_ws;
    int* map1 = map0 + NN;
    unsigned short* new0b = (unsigned short*)(map1 + NN);
    unsigned short* Qw0b = new0b + (size_t)N0 * F;
    unsigned short* Qw1b = Qw0b + 128 * 128;
    unsigned short* Ww0b = Qw1b + 128 * 128;
    unsigned short* Ww1b = Ww0b + 128 * 256;

    hipMemsetAsync(map0, 0xFF, (size_t)2 * NN * sizeof(int), stream);
    k_prep<<<64, 256, 0, stream>>>(ns0, ns1, map0, map1,
                                   Qw0, Qw1, Ww0, Ww1, Qw0b, Qw1b, Ww0b, Ww1b);

    // layer 0 (reads original h; writes new0 bf16)
    k_layer<<<N0 / 16, 512, 0, stream>>>(h, nullptr, nullptr, ns0, nb0, nbw0,
                                         Qw0b, Qb0, Ww0b, Wb0, nullptr, new0b);

    // layer 1 (h with nodeset0 rows redirected to new0b; writes d_out f32)
    k_layer<<<N1 / 16, 512, 0, stream>>>(h, new0b, map0, ns1, nb1, nbw1,
                                         Qw1b, Qb1, Ww1b, Wb1, (float*)d_out, nullptr);

    k_fix<<<(N1 + 255) / 256, 256, 0, stream>>>(map1, ns1, (float*)d_out, N1);
}

// Round 6
// 78.991 us; speedup vs baseline: 1.3414x; 1.1576x over previous
//
#include <hip/hip_runtime.h>
#include <hip/hip_bf16.h>
#include <math.h>

#define NN 1000000
#define F 128
#define N0 16384
#define N1 4096

typedef __attribute__((ext_vector_type(8))) short bf16x8;
typedef __attribute__((ext_vector_type(4))) float f32x4;

__device__ inline unsigned short f2b(float f) {
    union { float f; unsigned u; } v; v.f = f;
    unsigned r = v.u + 0x7FFFu + ((v.u >> 16) & 1u);
    return (unsigned short)(r >> 16);
}

__device__ inline bf16x8 pack8(float4 a, float4 b) {
    union { __hip_bfloat162 h2[4]; bf16x8 v; } u;
    u.h2[0] = __float22bfloat162_rn(make_float2(a.x, a.y));
    u.h2[1] = __float22bfloat162_rn(make_float2(a.z, a.w));
    u.h2[2] = __float22bfloat162_rn(make_float2(b.x, b.y));
    u.h2[3] = __float22bfloat162_rn(make_float2(b.z, b.w));
    return u.v;
}

// ---------------- prep: maps (last-wins) + weight bf16 conversion ------------
// maps pre-initialized to -1 via hipMemsetAsync(0xFF)

__global__ void k_prep(const int* __restrict__ ns0, const int* __restrict__ ns1,
                       int* __restrict__ map0, int* __restrict__ map1,
                       const float* __restrict__ Qw0, const float* __restrict__ Qw1,
                       const float* __restrict__ Ww0, const float* __restrict__ Ww1,
                       unsigned short* __restrict__ Qw0b, unsigned short* __restrict__ Qw1b,
                       unsigned short* __restrict__ Ww0b, unsigned short* __restrict__ Ww1b) {
    int i = blockIdx.x * blockDim.x + threadIdx.x;
    int nt = gridDim.x * blockDim.x;
    if (i < N0) atomicMax(&map0[ns0[i]], i);
    if (i < N1) atomicMax(&map1[ns1[i]], i);
    for (int j = i; j < 128 * 128; j += nt) { Qw0b[j] = f2b(Qw0[j]); Qw1b[j] = f2b(Qw1[j]); }
    for (int j = i; j < 128 * 256; j += nt) { Ww0b[j] = f2b(Ww0[j]); Ww1b[j] = f2b(Ww1[j]); }
}

// ---------------- fused layer: qagg (phase 1) + dense (phase 2) --------------
// block = 512 threads (8 waves) = 16 nodes. VGPR-capped for 2 blocks/CU.

__global__ __launch_bounds__(512, 4) void k_layer(
    const float* __restrict__ h, const unsigned short* __restrict__ newprevb,
    const int* __restrict__ mapprev,
    const int* __restrict__ nodeset, const int* __restrict__ nb,
    const float* __restrict__ nbw,
    const unsigned short* __restrict__ Qwb, const float* __restrict__ Qb,
    const unsigned short* __restrict__ Wwb, const float* __restrict__ Wb,
    float* __restrict__ outf, unsigned short* __restrict__ outb)
{
    __shared__ unsigned short lQ[128 * 128];   // 32 KB Qw bf16, XOR-swizzled
    __shared__ unsigned short lA[16 * 256];    // 8 KB: [node][self 0..127 | agg 128..255]
    __shared__ float sred[8][16];
    const int tid = threadIdx.x;
    const int wid = tid >> 6, lane = tid & 63;
    const int row = lane & 15, kg = lane >> 4;
    const long mbase = (long)blockIdx.x * 16;

    // ---- issue self-row gather (threads 0..127; 8 lanes per node row)
    float4 sv[4];
    uint4 sb[2];
    bool sredir = false;
    const int sq = tid & 7;
    if (tid < 128) {
        int sr = tid >> 3;
        int gs = nodeset[mbase + sr];
        int p = mapprev ? mapprev[gs] : -1;
        if (p >= 0) {
            sredir = true;
            const uint4* s = (const uint4*)(newprevb + (size_t)p * F + sq * 16);
            sb[0] = s[0]; sb[1] = s[1];
        } else {
            const float4* s = (const float4*)(h + (size_t)gs * F + sq * 16);
            sv[0] = s[0]; sv[1] = s[1]; sv[2] = s[2]; sv[3] = s[3];
        }
    }

    // ---- neighbor weights (issue early, tiny)
    const long nodebase = mbase + wid * 2;
    float w[2][4];
#pragma unroll
    for (int nn = 0; nn < 2; ++nn)
#pragma unroll
        for (int r = 0; r < 4; ++r) w[nn][r] = nbw[(nodebase + nn) * 16 + kg * 4 + r];

    // ---- issue neighbor gathers (2 nodes per wave), pack to bf16 promptly
    bf16x8 Ab[2][4];
    {
        float4 av[2][8];
        bool redir[2];
#pragma unroll
        for (int nn = 0; nn < 2; ++nn) {
            long node = nodebase + nn;
            int g = nb[node * 16 + row];
            int p = mapprev ? mapprev[g] : -1;
            redir[nn] = (p >= 0);
            if (p >= 0) {
                const bf16x8* s = (const bf16x8*)(newprevb + (size_t)p * F);
#pragma unroll
                for (int kk = 0; kk < 4; ++kk) Ab[nn][kk] = s[kk * 4 + kg];
            } else {
                const float4* s4 = (const float4*)(h + (size_t)g * F);
#pragma unroll
                for (int kk = 0; kk < 4; ++kk) {
                    av[nn][kk * 2]     = s4[kk * 8 + kg * 2];
                    av[nn][kk * 2 + 1] = s4[kk * 8 + kg * 2 + 1];
                }
            }
        }
#pragma unroll
        for (int nn = 0; nn < 2; ++nn)
            if (!redir[nn]) {
#pragma unroll
                for (int kk = 0; kk < 4; ++kk)
                    Ab[nn][kk] = pack8(av[nn][kk * 2], av[nn][kk * 2 + 1]);
            }
    }

    // ---- stage Qw into swizzled LDS
    for (int c = tid; c < 2048; c += 512) {
        int j = c >> 4;
        uint4 v = ((const uint4*)Qwb)[c];
        *(uint4*)((char*)lQ + ((c << 4) ^ ((j & 7) << 4))) = v;
    }

    // ---- write self rows to lA (bf16, swizzled)
    if (tid < 128) {
        int sr = tid >> 3;
        int b0 = sr * 512 + sq * 32;
        int swz = (sr & 7) << 4;
        if (sredir) {
            *(uint4*)((char*)lA + (b0 ^ swz)) = sb[0];
            *(uint4*)((char*)lA + ((b0 + 16) ^ swz)) = sb[1];
        } else {
            *(bf16x8*)((char*)lA + (b0 ^ swz)) = pack8(sv[0], sv[1]);
            *(bf16x8*)((char*)lA + ((b0 + 16) ^ swz)) = pack8(sv[2], sv[3]);
        }
    }
    __syncthreads();

    // ---- phase 1: qagg MFMA, split into two 64-col halves (acc = 32 VGPR)
    float inv[2];
#pragma unroll
    for (int nn = 0; nn < 2; ++nn) {
        float ws = w[nn][0] + w[nn][1] + w[nn][2] + w[nn][3];
        ws += __shfl_xor(ws, 16);
        ws += __shfl_xor(ws, 32);
        inv[nn] = (ws == 0.f) ? 1.f : 1.f / ws;
    }

#pragma unroll 1
    for (int half = 0; half < 2; ++half) {
        f32x4 acc[2][4];
#pragma unroll
        for (int nn = 0; nn < 2; ++nn)
#pragma unroll
            for (int jt = 0; jt < 4; ++jt)
                acc[nn][jt] = (f32x4){0.f, 0.f, 0.f, 0.f};

#pragma unroll
        for (int kk = 0; kk < 4; ++kk) {
            bf16x8 Bf[4];
#pragma unroll
            for (int jt = 0; jt < 4; ++jt) {
                int j = (half * 4 + jt) * 16 + row;
                int byte = ((j << 8) + (kk << 6) + (kg << 4)) ^ ((j & 7) << 4);
                Bf[jt] = *(bf16x8*)((char*)lQ + byte);
            }
#pragma unroll
            for (int jt = 0; jt < 4; ++jt) {
                acc[0][jt] = __builtin_amdgcn_mfma_f32_16x16x32_bf16(Ab[0][kk], Bf[jt], acc[0][jt], 0, 0, 0);
                acc[1][jt] = __builtin_amdgcn_mfma_f32_16x16x32_bf16(Ab[1][kk], Bf[jt], acc[1][jt], 0, 0, 0);
            }
        }

        // epilogue for this half: bias + leaky + weighted reduce -> lA agg (bf16)
#pragma unroll
        for (int nn = 0; nn < 2; ++nn) {
            int nl = wid * 2 + nn;
#pragma unroll
            for (int jt = 0; jt < 4; ++jt) {
                int jtg = half * 4 + jt;
                float qb = Qb[jtg * 16 + row];
                float t = 0.f;
#pragma unroll
                for (int r = 0; r < 4; ++r) {
                    float v = acc[nn][jt][r] + qb;
                    v = v > 0.f ? v : 0.01f * v;
                    t = fmaf(w[nn][r], v, t);
                }
                t += __shfl_xor(t, 16);
                t += __shfl_xor(t, 32);
                if (lane < 16) {
                    int byte = (nl * 512 + 256 + jtg * 32 + lane * 2) ^ ((nl & 7) << 4);
                    *(unsigned short*)((char*)lA + byte) = f2b(t * inv[nn]);
                }
            }
        }
    }
    __syncthreads();

    // ---- phase 2: dense 16x256 @ Ww^T, this wave = 16 output cols
    const int j = wid * 16 + row;
    f32x4 dacc = (f32x4){0.f, 0.f, 0.f, 0.f};
#pragma unroll
    for (int kk = 0; kk < 8; ++kk) {
        bf16x8 a = *(bf16x8*)((char*)lA + ((row * 512 + kk * 64 + kg * 16) ^ ((row & 7) << 4)));
        bf16x8 b = ((const bf16x8*)(Wwb + (size_t)j * 256))[kk * 4 + kg];
        dacc = __builtin_amdgcn_mfma_f32_16x16x32_bf16(a, b, dacc, 0, 0, 0);
    }

    float wb = Wb[j];
    float ss[4];
#pragma unroll
    for (int r = 0; r < 4; ++r) {
        float v = dacc[r] + wb;
        v = v > 0.f ? v : 0.01f * v;
        dacc[r] = v;
        ss[r] = v * v;
    }
#pragma unroll
    for (int r = 0; r < 4; ++r) {
        ss[r] += __shfl_xor(ss[r], 1);
        ss[r] += __shfl_xor(ss[r], 2);
        ss[r] += __shfl_xor(ss[r], 4);
        ss[r] += __shfl_xor(ss[r], 8);
    }
    if (row == 0) {
#pragma unroll
        for (int r = 0; r < 4; ++r) sred[wid][kg * 4 + r] = ss[r];
    }
    __syncthreads();
    float invn[4];
#pragma unroll
    for (int r = 0; r < 4; ++r) {
        float s = 0.f;
#pragma unroll
        for (int w8 = 0; w8 < 8; ++w8) s += sred[w8][kg * 4 + r];
        float n = sqrtf(s);
        invn[r] = (n == 0.f) ? 1.f : 1.f / n;
    }
    if (outf) {
#pragma unroll
        for (int r = 0; r < 4; ++r)
            outf[(size_t)(mbase + kg * 4 + r) * F + j] = dacc[r] * invn[r];
    } else {
#pragma unroll
        for (int r = 0; r < 4; ++r)
            outb[(size_t)(mbase + kg * 4 + r) * F + j] = f2b(dacc[r] * invn[r]);
    }
}

// ---------------- duplicate-row fixup on d_out -------------------------------

__global__ void k_fix(const int* __restrict__ map1, const int* __restrict__ ns1,
                      float* __restrict__ out, int n) {
    int i = blockIdx.x * blockDim.x + threadIdx.x;
    if (i < n) {
        int p = map1[ns1[i]];
        if (p != i) {
            float4* o = (float4*)out;
#pragma unroll
            for (int c = 0; c < 32; ++c) o[(size_t)i * 32 + c] = o[(size_t)p * 32 + c];
        }
    }
}

// ---------------- launcher ---------------------------------------------------

extern "C" void kernel_launch(void* const* d_in, const int* in_sizes, int n_in,
                              void* d_out, int out_size, void* d_ws, size_t ws_size,
                              hipStream_t stream) {
    const float* h    = (const float*)d_in[0];
    const float* Qw0  = (const float*)d_in[1];
    const float* Qb0  = (const float*)d_in[2];
    const float* Ww0  = (const float*)d_in[3];
    const float* Wb0  = (const float*)d_in[4];
    const float* Qw1  = (const float*)d_in[5];
    const float* Qb1  = (const float*)d_in[6];
    const float* Ww1  = (const float*)d_in[7];
    const float* Wb1  = (const float*)d_in[8];
    const int*   ns0  = (const int*)d_in[9];
    const int*   nb0  = (const int*)d_in[10];
    const float* nbw0 = (const float*)d_in[11];
    const int*   ns1  = (const int*)d_in[12];
    const int*   nb1  = (const int*)d_in[13];
    const float* nbw1 = (const float*)d_in[14];

    // ws: map0 | map1 | new0b bf16 | Qw0b | Qw1b | Ww0b | Ww1b
    int* map0 = (int*)d_ws;
    int* map1 = map0 + NN;
    unsigned short* new0b = (unsigned short*)(map1 + NN);
    unsigned short* Qw0b = new0b + (size_t)N0 * F;
    unsigned short* Qw1b = Qw0b + 128 * 128;
    unsigned short* Ww0b = Qw1b + 128 * 128;
    unsigned short* Ww1b = Ww0b + 128 * 256;

    hipMemsetAsync(map0, 0xFF, (size_t)2 * NN * sizeof(int), stream);
    k_prep<<<64, 256, 0, stream>>>(ns0, ns1, map0, map1,
                                   Qw0, Qw1, Ww0, Ww1, Qw0b, Qw1b, Ww0b, Ww1b);

    // layer 0 (reads original h; writes new0 bf16)
    k_layer<<<N0 / 16, 512, 0, stream>>>(h, nullptr, nullptr, ns0, nb0, nbw0,
                                         Qw0b, Qb0, Ww0b, Wb0, nullptr, new0b);

    // layer 1 (h with nodeset0 rows redirected to new0b; writes d_out f32)
    k_layer<<<N1 / 16, 512, 0, stream>>>(h, new0b, map0, ns1, nb1, nbw1,
                                         Qw1b, Qb1, Ww1b, Wb1, (float*)d_out, nullptr);

    k_fix<<<(N1 + 255) / 256, 256, 0, stream>>>(map1, ns1, (float*)d_out, N1);
}